// Round 1
// baseline (571.471 us; speedup 1.0000x reference)
//
#include <hip/hip_runtime.h>

#define BB    16
#define TT    64
#define F0    8
#define NN    100
#define NEX   15
#define F1    32
#define F2    64
#define K1    4
#define K2    3
#define HRD   64
#define OUTD  5
#define BT    (BB*TT)        // 1024
#define MROWS (BT*NN)        // 102400
#define ZELEMS ((size_t)BT*F0*NEX*NN)   // 12,288,000 floats

// ---------------------------------------------------------------------------
// Head: delayed diffusion along diagonal chains.
// Block c = (b, t0) with t0 in [1,63]; computes z_k[b, t0+k-1] for k=1..15
// (truncated at t=T-1). z lives in LDS as [n][f] (32B rows -> b128 broadcasts).
// Each S[b,t] matrix is read exactly once per chain (coalesced over lanes m).
// z_k[b,t] for t<k is identically zero and never stored (consumer guards).
// ---------------------------------------------------------------------------
__global__ __launch_bounds__(128) void head_chain(
    const float* __restrict__ x, const float* __restrict__ S,
    float* __restrict__ zbuf) {
  __shared__ float zl[NN * F0];          // zl[n*8 + f]
  const int c  = blockIdx.x;
  const int b  = c / (TT - 1);
  const int t0 = 1 + (c - b * (TT - 1));
  const int m  = threadIdx.x;

  if (m < NN) {
    const float* xp = x + ((size_t)(b * TT + t0 - 1) * F0) * NN + m;
#pragma unroll
    for (int f = 0; f < F0; ++f) zl[m * F0 + f] = xp[(size_t)f * NN];
  }
  __syncthreads();

  for (int k = 1; k <= NEX; ++k) {
    const int t = t0 + k - 1;            // uniform across the block
    if (t >= TT) break;
    float acc[F0];
#pragma unroll
    for (int f = 0; f < F0; ++f) acc[f] = 0.f;
    if (m < NN) {
      const float* Sp = S + (size_t)(b * TT + t) * NN * NN + m;
#pragma unroll 4
      for (int n = 0; n < NN; ++n) {
        const float s = Sp[(size_t)n * NN];    // coalesced over lanes m
#pragma unroll
        for (int f = 0; f < F0; ++f) acc[f] += zl[n * F0 + f] * s;  // LDS bcast
      }
    }
    __syncthreads();                     // all reads of zl done
    if (m < NN) {
#pragma unroll
      for (int f = 0; f < F0; ++f) zl[m * F0 + f] = acc[f];
      // zbuf layout: [bt][f][k-1][n]
      float* zp = zbuf + (((size_t)(b * TT + t) * F0) * NEX + (k - 1)) * NN + m;
#pragma unroll
      for (int f = 0; f < F0; ++f) zp[(size_t)f * NEX * NN] = acc[f];
    }
    __syncthreads();                     // zl updated for next step
  }
}

// ---------------------------------------------------------------------------
// Tail 1: conv1 (8ch,K=4) + ReLU + maxpool2 per row -> y1 [bt][32*6][n]
// Thread per row; z row (128 f32) in registers; weight indices wave-uniform.
// ---------------------------------------------------------------------------
__global__ __launch_bounds__(256) void conv1_k(
    const float* __restrict__ x, const float* __restrict__ zbuf,
    const float* __restrict__ w1, const float* __restrict__ b1,
    float* __restrict__ y1g) {
  const int row = blockIdx.x * 256 + threadIdx.x;
  if (row >= MROWS) return;
  const int bt = row / NN;
  const int n  = row - bt * NN;
  const int t  = bt & (TT - 1);

  float zr[F0][NEX + 1];
#pragma unroll
  for (int f = 0; f < F0; ++f) {
    zr[f][0] = x[((size_t)bt * F0 + f) * NN + n];
#pragma unroll
    for (int k = 1; k <= NEX; ++k)
      zr[f][k] = (k <= t)
          ? zbuf[(((size_t)bt * F0 + f) * NEX + (k - 1)) * NN + n]
          : 0.f;
  }

  float* yout = y1g + (size_t)bt * (F1 * 6) * NN + n;
  for (int co = 0; co < F1; ++co) {
    const float bias = b1[co];
    float c1[12];                        // conv pos 12 is dropped by the pool
#pragma unroll
    for (int l = 0; l < 12; ++l) c1[l] = bias;
#pragma unroll
    for (int ci = 0; ci < F0; ++ci)
#pragma unroll
      for (int kk = 0; kk < K1; ++kk) {
        const float w = w1[(co * F0 + ci) * K1 + kk];   // uniform -> s_load
#pragma unroll
        for (int l = 0; l < 12; ++l) c1[l] += zr[ci][l + kk] * w;
      }
#pragma unroll
    for (int p = 0; p < 6; ++p)
      yout[(size_t)(co * 6 + p) * NN] =
          fmaxf(fmaxf(c1[2 * p], c1[2 * p + 1]), 0.f);
  }
}

// ---------------------------------------------------------------------------
// Tail 2: conv2 (32ch,K=3) + ReLU + maxpool2 + fc1(128->64,ReLU) + fc2(64->5)
// Thread per row. conv2 in co2-chunks of 8 (acc fits regs); fc2 fused into
// fc1's j-loop so h is never materialized. All reg arrays statically indexed.
// ---------------------------------------------------------------------------
__global__ __launch_bounds__(256) void conv2_fc_k(
    const float* __restrict__ y1g,
    const float* __restrict__ w2,  const float* __restrict__ b2,
    const float* __restrict__ fw1, const float* __restrict__ fb1,
    const float* __restrict__ fw2, const float* __restrict__ fb2,
    float* __restrict__ out) {
  const int row = blockIdx.x * 256 + threadIdx.x;
  if (row >= MROWS) return;
  const int bt = row / NN;
  const int n  = row - bt * NN;
  const float* yin = y1g + (size_t)bt * (F1 * 6) * NN + n;

  float y2[F2 * 2];
#pragma unroll
  for (int cc = 0; cc < F2; cc += 8) {
    float acc[8][4];
#pragma unroll
    for (int j = 0; j < 8; ++j) {
      const float bb = b2[cc + j];
#pragma unroll
      for (int l = 0; l < 4; ++l) acc[j][l] = bb;
    }
    for (int ci = 0; ci < F1; ++ci) {
      float yv[6];
#pragma unroll
      for (int l = 0; l < 6; ++l) yv[l] = yin[(size_t)(ci * 6 + l) * NN];
#pragma unroll
      for (int j = 0; j < 8; ++j)
#pragma unroll
        for (int kk = 0; kk < K2; ++kk) {
          const float w = w2[((cc + j) * F1 + ci) * K2 + kk]; // uniform
#pragma unroll
          for (int l = 0; l < 4; ++l) acc[j][l] += yv[l + kk] * w;
        }
    }
#pragma unroll
    for (int j = 0; j < 8; ++j) {
      y2[(cc + j) * 2 + 0] = fmaxf(fmaxf(acc[j][0], acc[j][1]), 0.f);
      y2[(cc + j) * 2 + 1] = fmaxf(fmaxf(acc[j][2], acc[j][3]), 0.f);
    }
  }

  float o[OUTD];
#pragma unroll
  for (int q = 0; q < OUTD; ++q) o[q] = fb2[q];
  for (int j = 0; j < HRD; ++j) {
    float h = fb1[j];
#pragma unroll
    for (int d = 0; d < F2 * 2; ++d) h += y2[d] * fw1[j * (F2 * 2) + d];
    h = fmaxf(h, 0.f);
#pragma unroll
    for (int q = 0; q < OUTD; ++q) o[q] += h * fw2[q * HRD + j];
  }
#pragma unroll
  for (int q = 0; q < OUTD; ++q)
    out[((size_t)bt * OUTD + q) * NN + n] = o[q];
}

// ---------------------------------------------------------------------------
extern "C" void kernel_launch(void* const* d_in, const int* in_sizes, int n_in,
                              void* d_out, int out_size, void* d_ws,
                              size_t ws_size, hipStream_t stream) {
  const float* x   = (const float*)d_in[0];
  const float* S   = (const float*)d_in[1];
  const float* w1  = (const float*)d_in[2];
  const float* b1  = (const float*)d_in[3];
  const float* w2  = (const float*)d_in[4];
  const float* b2  = (const float*)d_in[5];
  const float* fw1 = (const float*)d_in[6];
  const float* fb1 = (const float*)d_in[7];
  const float* fw2 = (const float*)d_in[8];
  const float* fb2 = (const float*)d_in[9];

  float* zbuf = (float*)d_ws;                 // 12,288,000 f32 = 49.2 MB
  float* y1g  = zbuf + ZELEMS;                // 19,660,800 f32 = 78.6 MB
  float* outp = (float*)d_out;

  head_chain<<<BB * (TT - 1), 128, 0, stream>>>(x, S, zbuf);
  conv1_k<<<MROWS / 256, 256, 0, stream>>>(x, zbuf, w1, b1, y1g);
  conv2_fc_k<<<MROWS / 256, 256, 0, stream>>>(y1g, w2, b2, fw1, fb1, fw2, fb2,
                                              outp);
}

// Round 2
// 269.967 us; speedup vs baseline: 2.1168x; 2.1168x over previous
//
#include <hip/hip_runtime.h>

#define BB    16
#define TT    64
#define F0    8
#define NN    100
#define NEX   15
#define F1    32
#define F2    64
#define K1    4
#define K2    3
#define HRD   64
#define OUTD  5
#define BT    (BB*TT)        // 1024
#define MROWS (BT*NN)        // 102400
#define ZELEMS  ((size_t)BT*F0*NEX*NN)    // 12,288,000 floats (49.2 MB)
#define Y1ELEMS ((size_t)BT*F1*6*NN)      // 19,660,800 floats (78.6 MB)
#define Y2ELEMS ((size_t)MROWS*128)       // 13,107,200 floats (52.4 MB)

// ---------------------------------------------------------------------------
// Head: delayed diffusion along diagonal chains (unchanged structure,
// deeper unroll: 20 S-loads in flight per batch instead of 4).
// ---------------------------------------------------------------------------
__global__ __launch_bounds__(128) void head_chain(
    const float* __restrict__ x, const float* __restrict__ S,
    float* __restrict__ zbuf) {
  __shared__ float zl[NN * F0];          // zl[n*8 + f]
  const int c  = blockIdx.x;
  const int b  = c / (TT - 1);
  const int t0 = 1 + (c - b * (TT - 1));
  const int m  = threadIdx.x;

  if (m < NN) {
    const float* xp = x + ((size_t)(b * TT + t0 - 1) * F0) * NN + m;
#pragma unroll
    for (int f = 0; f < F0; ++f) zl[m * F0 + f] = xp[(size_t)f * NN];
  }
  __syncthreads();

  for (int k = 1; k <= NEX; ++k) {
    const int t = t0 + k - 1;            // uniform across the block
    if (t >= TT) break;
    float acc[F0];
#pragma unroll
    for (int f = 0; f < F0; ++f) acc[f] = 0.f;
    if (m < NN) {
      const float* Sp = S + (size_t)(b * TT + t) * NN * NN + m;
#pragma unroll 20
      for (int n = 0; n < NN; ++n) {
        const float s = Sp[(size_t)n * NN];    // coalesced over lanes m
#pragma unroll
        for (int f = 0; f < F0; ++f) acc[f] += zl[n * F0 + f] * s;  // LDS bcast
      }
    }
    __syncthreads();
    if (m < NN) {
#pragma unroll
      for (int f = 0; f < F0; ++f) zl[m * F0 + f] = acc[f];
      float* zp = zbuf + (((size_t)(b * TT + t) * F0) * NEX + (k - 1)) * NN + m;
#pragma unroll
      for (int f = 0; f < F0; ++f) zp[(size_t)f * NEX * NN] = acc[f];
    }
    __syncthreads();
  }
}

// ---------------------------------------------------------------------------
// Tail 1: conv1 + ReLU + pool2, chunked over co (gridDim.y=4, 8 co each).
// ---------------------------------------------------------------------------
__global__ __launch_bounds__(256) void conv1_k(
    const float* __restrict__ x, const float* __restrict__ zbuf,
    const float* __restrict__ w1, const float* __restrict__ b1,
    float* __restrict__ y1g) {
  const int row = blockIdx.x * 256 + threadIdx.x;
  if (row >= MROWS) return;
  const int cc = blockIdx.y * 8;
  const int bt = row / NN;
  const int n  = row - bt * NN;
  const int t  = bt & (TT - 1);

  float acc[8][12];
#pragma unroll
  for (int j = 0; j < 8; ++j) {
    const float bias = b1[cc + j];
#pragma unroll
    for (int l = 0; l < 12; ++l) acc[j][l] = bias;
  }

  for (int ci = 0; ci < F0; ++ci) {
    float zv[NEX + 1];
    zv[0] = x[((size_t)bt * F0 + ci) * NN + n];
#pragma unroll
    for (int k = 1; k <= NEX; ++k)
      zv[k] = (k <= t)
          ? zbuf[(((size_t)bt * F0 + ci) * NEX + (k - 1)) * NN + n]
          : 0.f;
#pragma unroll
    for (int j = 0; j < 8; ++j)
#pragma unroll
      for (int kk = 0; kk < K1; ++kk) {
        const float w = w1[((cc + j) * F0 + ci) * K1 + kk];  // uniform
#pragma unroll
        for (int l = 0; l < 12; ++l) acc[j][l] += zv[l + kk] * w;
      }
  }

  float* yout = y1g + (size_t)bt * (F1 * 6) * NN + n;
#pragma unroll
  for (int j = 0; j < 8; ++j)
#pragma unroll
    for (int p = 0; p < 6; ++p)
      yout[(size_t)((cc + j) * 6 + p) * NN] =
          fmaxf(fmaxf(acc[j][2 * p], acc[j][2 * p + 1]), 0.f);
}

// ---------------------------------------------------------------------------
// Tail 2: conv2 + ReLU + pool2, chunked over co (gridDim.y=4, 16 co each).
// Writes y2 [bt][128][n].
// ---------------------------------------------------------------------------
__global__ __launch_bounds__(256) void conv2_k(
    const float* __restrict__ y1g,
    const float* __restrict__ w2, const float* __restrict__ b2,
    float* __restrict__ y2g) {
  const int row = blockIdx.x * 256 + threadIdx.x;
  if (row >= MROWS) return;
  const int cc = blockIdx.y * 16;
  const int bt = row / NN;
  const int n  = row - bt * NN;
  const float* yin = y1g + (size_t)bt * (F1 * 6) * NN + n;

  float acc[16][4];
#pragma unroll
  for (int j = 0; j < 16; ++j) {
    const float bb = b2[cc + j];
#pragma unroll
    for (int l = 0; l < 4; ++l) acc[j][l] = bb;
  }
  for (int ci = 0; ci < F1; ++ci) {
    float yv[6];
#pragma unroll
    for (int l = 0; l < 6; ++l) yv[l] = yin[(size_t)(ci * 6 + l) * NN];
#pragma unroll
    for (int j = 0; j < 16; ++j)
#pragma unroll
      for (int kk = 0; kk < K2; ++kk) {
        const float w = w2[((cc + j) * F1 + ci) * K2 + kk];  // uniform
#pragma unroll
        for (int l = 0; l < 4; ++l) acc[j][l] += yv[l + kk] * w;
      }
  }
  float* yo = y2g + ((size_t)bt * 128) * NN + n;
#pragma unroll
  for (int j = 0; j < 16; ++j) {
    yo[(size_t)((cc + j) * 2 + 0) * NN] =
        fmaxf(fmaxf(acc[j][0], acc[j][1]), 0.f);
    yo[(size_t)((cc + j) * 2 + 1) * NN] =
        fmaxf(fmaxf(acc[j][2], acc[j][3]), 0.f);
  }
}

// ---------------------------------------------------------------------------
// Tail 3: fc1(128->64,ReLU) + fc2(64->5). j-outer, y2 row in registers so
// fw1 rows are contiguous uniform s_loads. 4-way split accumulator per j.
// ---------------------------------------------------------------------------
__global__ __launch_bounds__(256) void fc_k(
    const float* __restrict__ y2g,
    const float* __restrict__ fw1, const float* __restrict__ fb1,
    const float* __restrict__ fw2, const float* __restrict__ fb2,
    float* __restrict__ out) {
  const int row = blockIdx.x * 256 + threadIdx.x;
  if (row >= MROWS) return;
  const int bt = row / NN;
  const int n  = row - bt * NN;
  const float* yi = y2g + ((size_t)bt * 128) * NN + n;

  float v[128];
#pragma unroll
  for (int d = 0; d < 128; ++d) v[d] = yi[(size_t)d * NN];

  float o[OUTD];
#pragma unroll
  for (int q = 0; q < OUTD; ++q) o[q] = fb2[q];

  for (int j = 0; j < HRD; ++j) {
    const float* wr = fw1 + j * 128;     // uniform, contiguous -> s_load_x16
    float s0 = 0.f, s1 = 0.f, s2 = 0.f, s3 = 0.f;
#pragma unroll
    for (int d = 0; d < 128; d += 4) {
      s0 += v[d + 0] * wr[d + 0];
      s1 += v[d + 1] * wr[d + 1];
      s2 += v[d + 2] * wr[d + 2];
      s3 += v[d + 3] * wr[d + 3];
    }
    const float h = fmaxf((s0 + s1) + (s2 + s3) + fb1[j], 0.f);
#pragma unroll
    for (int q = 0; q < OUTD; ++q) o[q] += h * fw2[q * HRD + j];
  }
#pragma unroll
  for (int q = 0; q < OUTD; ++q)
    out[((size_t)bt * OUTD + q) * NN + n] = o[q];
}

// ---------------------------------------------------------------------------
// Fallback tail (round-1 monolithic conv2+fc) if ws is too small for y2.
// ---------------------------------------------------------------------------
__global__ __launch_bounds__(256) void conv2_fc_fallback(
    const float* __restrict__ y1g,
    const float* __restrict__ w2,  const float* __restrict__ b2,
    const float* __restrict__ fw1, const float* __restrict__ fb1,
    const float* __restrict__ fw2, const float* __restrict__ fb2,
    float* __restrict__ out) {
  const int row = blockIdx.x * 256 + threadIdx.x;
  if (row >= MROWS) return;
  const int bt = row / NN;
  const int n  = row - bt * NN;
  const float* yin = y1g + (size_t)bt * (F1 * 6) * NN + n;

  float y2[F2 * 2];
#pragma unroll
  for (int cc = 0; cc < F2; cc += 8) {
    float acc[8][4];
#pragma unroll
    for (int j = 0; j < 8; ++j) {
      const float bb = b2[cc + j];
#pragma unroll
      for (int l = 0; l < 4; ++l) acc[j][l] = bb;
    }
    for (int ci = 0; ci < F1; ++ci) {
      float yv[6];
#pragma unroll
      for (int l = 0; l < 6; ++l) yv[l] = yin[(size_t)(ci * 6 + l) * NN];
#pragma unroll
      for (int j = 0; j < 8; ++j)
#pragma unroll
        for (int kk = 0; kk < K2; ++kk) {
          const float w = w2[((cc + j) * F1 + ci) * K2 + kk];
#pragma unroll
          for (int l = 0; l < 4; ++l) acc[j][l] += yv[l + kk] * w;
        }
    }
#pragma unroll
    for (int j = 0; j < 8; ++j) {
      y2[(cc + j) * 2 + 0] = fmaxf(fmaxf(acc[j][0], acc[j][1]), 0.f);
      y2[(cc + j) * 2 + 1] = fmaxf(fmaxf(acc[j][2], acc[j][3]), 0.f);
    }
  }
  float o[OUTD];
#pragma unroll
  for (int q = 0; q < OUTD; ++q) o[q] = fb2[q];
  for (int j = 0; j < HRD; ++j) {
    float h = fb1[j];
#pragma unroll
    for (int d = 0; d < F2 * 2; ++d) h += y2[d] * fw1[j * (F2 * 2) + d];
    h = fmaxf(h, 0.f);
#pragma unroll
    for (int q = 0; q < OUTD; ++q) o[q] += h * fw2[q * HRD + j];
  }
#pragma unroll
  for (int q = 0; q < OUTD; ++q)
    out[((size_t)bt * OUTD + q) * NN + n] = o[q];
}

// ---------------------------------------------------------------------------
extern "C" void kernel_launch(void* const* d_in, const int* in_sizes, int n_in,
                              void* d_out, int out_size, void* d_ws,
                              size_t ws_size, hipStream_t stream) {
  const float* x   = (const float*)d_in[0];
  const float* S   = (const float*)d_in[1];
  const float* w1  = (const float*)d_in[2];
  const float* b1  = (const float*)d_in[3];
  const float* w2  = (const float*)d_in[4];
  const float* b2  = (const float*)d_in[5];
  const float* fw1 = (const float*)d_in[6];
  const float* fb1 = (const float*)d_in[7];
  const float* fw2 = (const float*)d_in[8];
  const float* fb2 = (const float*)d_in[9];

  float* zbuf = (float*)d_ws;
  float* y1g  = zbuf + ZELEMS;
  float* y2g  = y1g + Y1ELEMS;
  float* outp = (float*)d_out;
  const size_t need = (ZELEMS + Y1ELEMS + Y2ELEMS) * sizeof(float);

  head_chain<<<BB * (TT - 1), 128, 0, stream>>>(x, S, zbuf);
  conv1_k<<<dim3(MROWS / 256, 4), 256, 0, stream>>>(x, zbuf, w1, b1, y1g);
  if (ws_size >= need) {
    conv2_k<<<dim3(MROWS / 256, 4), 256, 0, stream>>>(y1g, w2, b2, y2g);
    fc_k<<<MROWS / 256, 256, 0, stream>>>(y2g, fw1, fb1, fw2, fb2, outp);
  } else {
    conv2_fc_fallback<<<MROWS / 256, 256, 0, stream>>>(
        y1g, w2, b2, fw1, fb1, fw2, fb2, outp);
  }
}